// Round 4
// baseline (17.065 us; speedup 1.0000x reference)
//
#include <hip/hip_runtime.h>

#define NPAIRS 460
#define NCLASS 10
#define PIX    3072
#define BATCH  1024
#define TPB    512
#define RPB    2                 // rows per block
#define NF4    (NPAIRS * 5)      // 2300 float4 per row

// async global->LDS stage of one 12KB pixel row (12 chunks of 1KB).
// LDS dest = wave-uniform base + lane*16 ; global src is per-lane.
__device__ __forceinline__ void stage_row(const float* __restrict__ xrow,
                                          float* __restrict__ lds_buf,
                                          int wave, int lane)
{
    for (int c = wave; c < 12; c += 8) {      // wave-uniform chunk index
        const float* gp = xrow + c * 256 + lane * 4;   // 16B per lane
        float*       lp = lds_buf + c * 256;           // uniform across wave
        __builtin_amdgcn_global_load_lds(
            (const __attribute__((address_space(1))) unsigned int*)((const void*)gp),
            (__attribute__((address_space(3))) unsigned int*)((void*)lp),
            16, 0, 0);
    }
}

__global__ __launch_bounds__(TPB) void
qmem_kernel(const float* __restrict__ x,
            const float* __restrict__ theta,
            const int2*  __restrict__ pidx,
            float4* __restrict__ out)
{
    __shared__ float s_x[2][PIX];             // 24 KB double-buffered row
    __shared__ float s_ct[NCLASS], s_st[NCLASS];

    const int t    = threadIdx.x;
    const int wave = t >> 6;
    const int lane = t & 63;
    const int row0 = blockIdx.x * RPB;

    if (t < NCLASS) {
        float s, c;
        __sincosf(theta[t], &s, &c);          // full-angle cos/sin(theta)
        s_ct[t] = c;
        s_st[t] = s;
    }

    // prologue: stage first row
    stage_row(x + (size_t)row0 * PIX, &s_x[0][0], wave, lane);
    __syncthreads();                          // drains vmcnt+lgkmcnt

    for (int r = 0; r < RPB; ++r) {
        const int row = row0 + r;
        const int cur = r & 1;

        // prefetch next row while we compute+store this one
        if (r + 1 < RPB)
            stage_row(x + (size_t)(row + 1) * PIX, &s_x[cur ^ 1][0], wave, lane);

        const float* sx   = &s_x[cur][0];
        const int2*  prow = pidx + (size_t)row * NPAIRS;
        float4*      og   = out + (size_t)row * NF4;

        // each thread owns consecutive output float4s (coalesced stores).
        // float4 j -> pair p=j/5, elems k..k+3, k=(j%5)*4 (never crosses pair).
        for (int j = t; j < NF4; j += TPB) {
            int p = j / 5;
            int k = (j - p * 5) * 4;
            int2 pi = prow[p];                // 5 lanes share one int2 (L1/L2)
            float sa, ca, sb, cb;
            __sincosf(sx[pi.x], &sa, &ca);
            __sincosf(sx[pi.y], &sb, &cb);
            float sasb = sa * sb;
            float o1   = fmaf(0.5f, ca * cb, 0.5f);   // (z1+1)/2

            float4 v;
            float* vp = (float*)&v;
#pragma unroll
            for (int e = 0; e < 4; ++e) {
                int c = k + e;                // output channel 0..19
                vp[e] = (c < NCLASS)
                      ? fmaf(0.5f, s_ct[c] * ca - s_st[c] * sasb, 0.5f)
                      : o1;
            }
            og[j] = v;
        }
        __syncthreads();                      // next-row prefetch complete
    }
}

extern "C" void kernel_launch(void* const* d_in, const int* in_sizes, int n_in,
                              void* d_out, int out_size, void* d_ws, size_t ws_size,
                              hipStream_t stream) {
    const float* x     = (const float*)d_in[0];
    const float* theta = (const float*)d_in[1];
    const int2*  pidx  = (const int2*)d_in[2];
    float4* out = (float4*)d_out;

    qmem_kernel<<<BATCH / RPB, TPB, 0, stream>>>(x, theta, pidx, out);
}

// Round 6
// 13.434 us; speedup vs baseline: 1.2703x; 1.2703x over previous
//
#include <hip/hip_runtime.h>

#define NPAIRS 460
#define NCLASS 10
#define PIX    3072
#define BATCH  1024
#define TPB    512
#define NF4    (NPAIRS * 5)    // 2300 float4 per batch row

typedef float vfloat4 __attribute__((ext_vector_type(4)));   // native vec for nt store

__global__ __launch_bounds__(TPB) void
qmem_kernel(const float* __restrict__ x,
            const float* __restrict__ theta,
            const int2*  __restrict__ pidx,
            vfloat4* __restrict__ out)
{
    __shared__ float s_x[PIX];        // 12 KB: one batch row of pixels
    __shared__ int2  s_pi[NPAIRS];    // 3.7 KB: this row's pair indices
    __shared__ float s_ct[NCLASS], s_st[NCLASS];

    const int b = blockIdx.x;
    const int t = threadIdx.x;

    // ---- stage pair indices first (their LDS writes drain under the x loads)
    const int2* prow = pidx + (size_t)b * NPAIRS;
    if (t < NPAIRS) s_pi[t] = prow[t];

    // ---- stage x[b] into LDS with float4 loads: 768 float4 per row
    const vfloat4* xrow = (const vfloat4*)(x + (size_t)b * PIX);
    vfloat4* sx4 = (vfloat4*)s_x;
    sx4[t] = xrow[t];                        // all 512 threads
    if (t < 256) sx4[t + 512] = xrow[t + 512];

    if (t < NCLASS) {
        float s, c;
        __sincosf(theta[t], &s, &c);         // full-angle cos(theta), sin(theta)
        s_ct[t] = c;
        s_st[t] = s;
    }
    __syncthreads();

    // ---- each thread owns consecutive output float4s: coalesced nt stores.
    // float4 j -> pair p = j/5, elems k..k+3 with k = (j%5)*4 (20%4==0:
    // a float4 never crosses a pair boundary).
    vfloat4* og = out + (size_t)b * NF4;
    for (int j = t; j < NF4; j += TPB) {
        int p = j / 5;
        int k = (j - p * 5) * 4;             // 0,4,8,12,16
        int2 pi = s_pi[p];
        float sa, ca, sb, cb;
        __sincosf(s_x[pi.x], &sa, &ca);
        __sincosf(s_x[pi.y], &sb, &cb);
        float sasb = sa * sb;
        float o1   = fmaf(0.5f, ca * cb, 0.5f);   // (z1+1)/2, class-independent

        vfloat4 v;
#pragma unroll
        for (int e = 0; e < 4; ++e) {
            int c = k + e;                   // output channel 0..19
            v[e] = (c < NCLASS)
                 ? fmaf(0.5f, s_ct[c] * ca - s_st[c] * sasb, 0.5f)
                 : o1;
        }
        __builtin_nontemporal_store(v, &og[j]);   // write-once: skip cache alloc
    }
}

extern "C" void kernel_launch(void* const* d_in, const int* in_sizes, int n_in,
                              void* d_out, int out_size, void* d_ws, size_t ws_size,
                              hipStream_t stream) {
    const float* x     = (const float*)d_in[0];
    const float* theta = (const float*)d_in[1];
    const int2*  pidx  = (const int2*)d_in[2];
    vfloat4* out = (vfloat4*)d_out;

    qmem_kernel<<<BATCH, TPB, 0, stream>>>(x, theta, pidx, out);
}